// Round 2
// baseline (14119.937 us; speedup 1.0000x reference)
//
#include <hip/hip_runtime.h>
#include <hip/hip_bf16.h>
#include <cstdint>
#include <cstddef>

#define Dm 1024
#define Sm 512
#define Bm 2
#define Nm 4096
#define Lm 4
#define Vm 32000

typedef __attribute__((ext_vector_type(8))) short short8;
typedef __attribute__((ext_vector_type(4))) float floatx4;

__device__ __forceinline__ unsigned short f2b(float f){
  union { float f; unsigned u; } v; v.f = f;
  unsigned r = (v.u + 0x7fffu + ((v.u >> 16) & 1u)) >> 16;
  return (unsigned short)r;
}

// Ternary decision at f64 precision: round(clip(w/s)) == sign(w) iff 2|w| > s.
// (f32->f64 promote exact, *2 exact; round-half-even sliver is 2^-53 wide -> ignorable.)
__device__ __forceinline__ float tern_q(float w, double s64){
  return ((double)fabsf(w) * 2.0 > s64) ? (w < 0.f ? -1.f : 1.f) : 0.f;
}

// ---------------- abs-sum reduction (for ternary scales) ----------------
// Deterministic fixed-order f64 accumulation; per-block partials, then a
// fixed-order finalize. Scale stays f64 end-to-end so the quantization
// boundary matches a float64 reference to ~1e-13 rel (zero expected flips).
__global__ __launch_bounds__(256) void absum_part_kernel(
    const float* __restrict__ x, long n4, double* __restrict__ part)
{
  long i = (long)blockIdx.x * blockDim.x + threadIdx.x;
  long stride = (long)gridDim.x * blockDim.x;
  double s = 0.0;
  for (; i < n4; i += stride){
    float4 v = ((const float4*)x)[i];
    s += (double)fabsf(v.x) + (double)fabsf(v.y)
       + (double)fabsf(v.z) + (double)fabsf(v.w);
  }
  #pragma unroll
  for (int off = 32; off; off >>= 1) s += __shfl_down(s, off, 64);
  __shared__ double wsum[4];
  int lane = threadIdx.x & 63, wv = threadIdx.x >> 6;
  if (lane == 0) wsum[wv] = s;
  __syncthreads();
  if (threadIdx.x == 0) part[blockIdx.x] = wsum[0]+wsum[1]+wsum[2]+wsum[3];
}

// one block per scale slot; reduces 512 double partials in fixed order
__global__ __launch_bounds__(256) void absum_final_kernel(
    const double* __restrict__ part, double* __restrict__ scales)
{
  const double* p = part + (size_t)blockIdx.x * 512;
  int tid = threadIdx.x;
  double s = p[tid] + p[tid + 256];
  #pragma unroll
  for (int off = 32; off; off >>= 1) s += __shfl_down(s, off, 64);
  __shared__ double wsum[4];
  int lane = tid & 63, wv = tid >> 6;
  if (lane == 0) wsum[wv] = s;
  __syncthreads();
  if (tid == 0) scales[blockIdx.x] = wsum[0]+wsum[1]+wsum[2]+wsum[3];
}

// ---------------- ternary embedding + positional ----------------
__global__ __launch_bounds__(256) void embed_kernel(
    const int* __restrict__ ids, const float* __restrict__ emb,
    const float* __restrict__ pos, const double* __restrict__ ssum,
    unsigned short* __restrict__ xb)
{
  int row = blockIdx.x;            // b*512 + s
  int sp  = row & (Sm - 1);
  int id  = ids[row];
  double s64 = ssum[0] / ((double)Vm * (double)Dm) + 1e-8;
  float s = (float)s64;
  int d = threadIdx.x * 4;
  float4 wv = *(const float4*)(emb + (size_t)id * Dm + d);
  float4 pv = *(const float4*)(pos + (size_t)sp * Dm + d);
  float y0 = s * tern_q(wv.x, s64) + pv.x;
  float y1 = s * tern_q(wv.y, s64) + pv.y;
  float y2 = s * tern_q(wv.z, s64) + pv.z;
  float y3 = s * tern_q(wv.w, s64) + pv.w;
  ushort4 u = make_ushort4(f2b(y0), f2b(y1), f2b(y2), f2b(y3));
  *(ushort4*)(xb + (size_t)row * Dm + d) = u;
}

// ---------------- bf16 MFMA GEMM: out = act(A @ W^T * s + bias) ----------------
// A: [M,K] bf16 (ushort). W: [N,K] f32, optionally ternarized (f64 boundary).
// 128x128 tile, 4 waves (2x2 of 64x64), 16x16x32 bf16 MFMA.
// Ternary q in {-1,0,1} staged exactly in bf16; scale applied to f32 acc.
__global__ __launch_bounds__(256) void gemm_kernel(
    const unsigned short* __restrict__ A, const float* __restrict__ W,
    const float* __restrict__ bias, const double* __restrict__ ssum, double cnt,
    int relu, float* __restrict__ outf, unsigned short* __restrict__ outb,
    int M, int N, int K)
{
  __shared__ unsigned short As[128][40];
  __shared__ unsigned short Bs[128][40];
  int tid = threadIdx.x;
  int wave = tid >> 6, lane = tid & 63;
  int wm = wave >> 1, wn = wave & 1;
  int bm = blockIdx.y, bn = blockIdx.x;

  bool tern = (ssum != nullptr);
  double s64 = 1.0;
  float s = 1.f;
  if (tern){ s64 = ssum[0] / cnt + 1e-8; s = (float)s64; }

  int arow = tid >> 1, achunk = tid & 1;
  const unsigned short* Ag = A + (size_t)(bm * 128 + arow) * K + achunk * 16;
  const float* Wg = W + (size_t)(bn * 128 + arow) * K + achunk * 16;

  floatx4 acc[4][4];
  #pragma unroll
  for (int i = 0; i < 4; i++)
    #pragma unroll
    for (int j = 0; j < 4; j++)
      acc[i][j] = (floatx4){0.f, 0.f, 0.f, 0.f};

  for (int k0 = 0; k0 < K; k0 += 32){
    __syncthreads();
    // stage A tile (bf16 already)
    uint4 a0 = *(const uint4*)(Ag + k0);
    uint4 a1 = *(const uint4*)(Ag + k0 + 8);
    *(uint4*)&As[arow][achunk * 16]     = a0;
    *(uint4*)&As[arow][achunk * 16 + 8] = a1;
    // stage W tile: f32 -> (ternary) -> bf16
    unsigned short tmp[16];
    #pragma unroll
    for (int q = 0; q < 4; q++){
      float4 wv = *(const float4*)(Wg + k0 + q * 4);
      float f0 = wv.x, f1 = wv.y, f2 = wv.z, f3 = wv.w;
      if (tern){
        f0 = tern_q(f0, s64);
        f1 = tern_q(f1, s64);
        f2 = tern_q(f2, s64);
        f3 = tern_q(f3, s64);
      }
      tmp[q*4+0] = f2b(f0); tmp[q*4+1] = f2b(f1);
      tmp[q*4+2] = f2b(f2); tmp[q*4+3] = f2b(f3);
    }
    *(uint4*)&Bs[arow][achunk * 16]     = *(uint4*)&tmp[0];
    *(uint4*)&Bs[arow][achunk * 16 + 8] = *(uint4*)&tmp[8];
    __syncthreads();

    int kq = lane >> 4, mr = lane & 15;
    short8 af[4], bf[4];
    #pragma unroll
    for (int i = 0; i < 4; i++) af[i] = *(const short8*)&As[wm*64 + i*16 + mr][kq*8];
    #pragma unroll
    for (int j = 0; j < 4; j++) bf[j] = *(const short8*)&Bs[wn*64 + j*16 + mr][kq*8];
    #pragma unroll
    for (int i = 0; i < 4; i++)
      #pragma unroll
      for (int j = 0; j < 4; j++)
        acc[i][j] = __builtin_amdgcn_mfma_f32_16x16x32_bf16(af[i], bf[j], acc[i][j], 0, 0, 0);
  }

  int cr = lane >> 4, cc = lane & 15;
  #pragma unroll
  for (int j = 0; j < 4; j++){
    int col = bn * 128 + wn * 64 + j * 16 + cc;
    float bv = bias ? bias[col] : 0.f;
    #pragma unroll
    for (int i = 0; i < 4; i++){
      #pragma unroll
      for (int r = 0; r < 4; r++){
        int row = bm * 128 + wm * 64 + i * 16 + cr * 4 + r;
        float v = acc[i][j][r] * s + bv;
        if (relu) v = fmaxf(v, 0.f);
        size_t idx = (size_t)row * N + col;
        if (outf) outf[idx] = v;
        if (outb) outb[idx] = f2b(v);
      }
    }
  }
}

// ---------------- persistent GRU over 512 steps ----------------
// 256 WGs x 512 threads. WG w owns h-dims [4w, 4w+4) -> 12 whh rows in registers.
// h double-buffered in global (relaxed agent atomics); per-WG release/acquire flags.
__global__ __launch_bounds__(512) void gru_kernel(
    const float* __restrict__ gi, const float* __restrict__ whh, const float* __restrict__ bhh,
    float* __restrict__ hbuf, int* __restrict__ flags,
    float* __restrict__ hs, unsigned short* __restrict__ hsb)
{
  __shared__ float lds_h[2 * Dm];
  __shared__ float lds_gh[24];
  int w = blockIdx.x, tid = threadIdx.x;
  int d0 = w * 4;
  int o = tid >> 4, c = tid & 15;     // dot o (24 dots), k-chunk c (16 chunks of 64)
  bool active = (tid < 384);
  int b = o / 12, r = o % 12;
  int g = r >> 2, dl = r & 3;
  int wrow = g * Dm + d0 + dl;
  float wreg[64];
  if (active){
    const float* src = whh + (size_t)wrow * Dm + c * 64;
    #pragma unroll
    for (int i = 0; i < 64; i++) wreg[i] = src[i];
  }
  float bhval = (active && c == 0) ? bhh[wrow] : 0.f;

  for (int t = 0; t < Sm; t++){
    if (t > 0 && tid < 256){
      int spins = 0;
      while (__hip_atomic_load(&flags[tid], __ATOMIC_ACQUIRE, __HIP_MEMORY_SCOPE_AGENT) < t){
        __builtin_amdgcn_s_sleep(1);
        if (++spins > (1 << 18)) break;   // safety: degrade to wrong answer, not hang
      }
    }
    __syncthreads();
    {
      const float* hsrc = hbuf + (t & 1) * 2048;
      for (int i = tid; i < 2048; i += 512)
        lds_h[i] = __hip_atomic_load(hsrc + i, __ATOMIC_RELAXED, __HIP_MEMORY_SCOPE_AGENT);
    }
    __syncthreads();
    float acc = 0.f;
    if (active){
      const float* hb = lds_h + b * Dm + c * 64;
      #pragma unroll
      for (int i = 0; i < 64; i++) acc += wreg[i] * hb[i];
    }
    #pragma unroll
    for (int off = 8; off; off >>= 1) acc += __shfl_xor(acc, off, 16);
    if (active && c == 0) lds_gh[o] = acc + bhval;
    __syncthreads();
    if (tid < 8){
      int bb = tid >> 2, dd = tid & 3;
      int d = d0 + dd;
      float gr = lds_gh[bb*12 + dd];
      float gz = lds_gh[bb*12 + 4 + dd];
      float gn = lds_gh[bb*12 + 8 + dd];
      const float* girow = gi + ((size_t)bb * Sm + t) * (3 * Dm);
      float ir = girow[d], iz = girow[Dm + d], inn = girow[2*Dm + d];
      float hv = lds_h[bb * Dm + d];
      float rr = 1.f / (1.f + expf(-(ir + gr)));
      float zz = 1.f / (1.f + expf(-(iz + gz)));
      float nn = tanhf(inn + rr * gn);
      float hnew = (1.f - zz) * nn + zz * hv;
      __hip_atomic_store(hbuf + ((t+1) & 1) * 2048 + bb * Dm + d, hnew,
                         __ATOMIC_RELAXED, __HIP_MEMORY_SCOPE_AGENT);
      size_t oi = ((size_t)bb * Sm + t) * Dm + d;
      hs[oi]  = hnew;
      hsb[oi] = f2b(hnew);
    }
    __syncthreads();
    if (tid == 0)
      __hip_atomic_store(&flags[w], t + 1, __ATOMIC_RELEASE, __HIP_MEMORY_SCOPE_AGENT);
  }
}

// ---------------- layernorm (+optional residual add), writes f32 + bf16 ----------------
__global__ __launch_bounds__(256) void ln_kernel(
    float* __restrict__ resid, const float* __restrict__ addv,
    const float* __restrict__ g, const float* __restrict__ b,
    float* __restrict__ outf, unsigned short* __restrict__ outb)
{
  int row = blockIdx.x;
  int d = threadIdx.x * 4;
  size_t base = (size_t)row * Dm + d;
  float4 v = *(float4*)(resid + base);
  if (addv){
    float4 a = *(const float4*)(addv + base);
    v.x += a.x; v.y += a.y; v.z += a.z; v.w += a.w;
  }
  float sum = v.x + v.y + v.z + v.w;
  float sq  = v.x*v.x + v.y*v.y + v.z*v.z + v.w*v.w;
  #pragma unroll
  for (int off = 32; off; off >>= 1){
    sum += __shfl_down(sum, off, 64);
    sq  += __shfl_down(sq,  off, 64);
  }
  __shared__ float red[4][2];
  __shared__ float bc[2];
  int lane = threadIdx.x & 63, wv = threadIdx.x >> 6;
  if (lane == 0){ red[wv][0] = sum; red[wv][1] = sq; }
  __syncthreads();
  if (threadIdx.x == 0){
    float st = red[0][0] + red[1][0] + red[2][0] + red[3][0];
    float qt = red[0][1] + red[1][1] + red[2][1] + red[3][1];
    float mu = st * (1.f / Dm);
    float var = qt * (1.f / Dm) - mu * mu;
    bc[0] = mu; bc[1] = rsqrtf(var + 1e-5f);
  }
  __syncthreads();
  float mu = bc[0], rs = bc[1];
  float4 gv = *(const float4*)(g + d);
  float4 bv = *(const float4*)(b + d);
  float4 y;
  y.x = (v.x - mu) * rs * gv.x + bv.x;
  y.y = (v.y - mu) * rs * gv.y + bv.y;
  y.z = (v.z - mu) * rs * gv.z + bv.z;
  y.w = (v.w - mu) * rs * gv.w + bv.w;
  if (outf) *(float4*)(outf + base) = y;
  if (outb){
    ushort4 u = make_ushort4(f2b(y.x), f2b(y.y), f2b(y.z), f2b(y.w));
    *(ushort4*)(outb + base) = u;
  }
}

extern "C" void kernel_launch(void* const* d_in, const int* in_sizes, int n_in,
                              void* d_out, int out_size, void* d_ws, size_t ws_size,
                              hipStream_t stream)
{
  const int*   ids    = (const int*)  d_in[0];
  const float* emb    = (const float*)d_in[1];
  const float* pos    = (const float*)d_in[2];
  const float* wih    = (const float*)d_in[3];
  const float* whh    = (const float*)d_in[4];
  const float* bih    = (const float*)d_in[5];
  const float* bhh    = (const float*)d_in[6];
  const float* syn_w  = (const float*)d_in[7];
  const float* syn_b  = (const float*)d_in[8];
  const float* out_w  = (const float*)d_in[9];
  const float* out_b  = (const float*)d_in[10];
  const float* ln_g   = (const float*)d_in[11];
  const float* ln_b   = (const float*)d_in[12];
  const float* on_g   = (const float*)d_in[13];
  const float* on_b   = (const float*)d_in[14];
  const float* head_w = (const float*)d_in[15];
  const float* head_b = (const float*)d_in[16];
  float* logits = (float*)d_out;

  char* ws = (char*)d_ws;
  double*         scales = (double*)ws;                        // 10 doubles
  int*            flags  = (int*)  (ws + 1024);                // 256 ints
  float*          hbuf   = (float*)(ws + 8192);                // 2*2048 f32
  double*         parts  = (double*)(ws + 24576);              // 10 slots x 512 doubles (40KB)
  unsigned short* xb     = (unsigned short*)(ws + 65536);      // [1024,1024] bf16 (2MB)
  float*          hs     = (float*)(ws + ((size_t)4  << 20));  // [1024,1024] f32  (4MB)
  unsigned short* hidden = (unsigned short*)(ws + ((size_t)12 << 20)); // [1024,4096] bf16 (8MB)
  float*          outbuf = (float*)(ws + ((size_t)20 << 20));  // [1024,1024] f32  (4MB)
  float*          gi     = (float*)(ws + ((size_t)24 << 20));  // [1024,3072] f32  (12MB)

  // zero scales + flags + hbuf
  hipMemsetAsync(d_ws, 0, 24576, stream);

  // ternary scale sums — deterministic fixed-order double reduction
  {
    long n;
    n = (long)Vm * Dm;
    absum_part_kernel<<<512, 256, 0, stream>>>(emb, n / 4, parts + 0 * 512);
    for (int l = 0; l < Lm; l++){
      n = (long)Nm * Dm;
      absum_part_kernel<<<512, 256, 0, stream>>>(syn_w + (size_t)l * Nm * Dm, n / 4, parts + (size_t)(1 + l) * 512);
      absum_part_kernel<<<512, 256, 0, stream>>>(out_w + (size_t)l * Dm * Nm, n / 4, parts + (size_t)(5 + l) * 512);
    }
    n = (long)Vm * Dm;
    absum_part_kernel<<<512, 256, 0, stream>>>(head_w, n / 4, parts + 9 * 512);
    absum_final_kernel<<<10, 256, 0, stream>>>(parts, scales);
  }

  // x = tern(emb)[ids] + pos  (bf16)
  embed_kernel<<<1024, 256, 0, stream>>>(ids, emb, pos, scales, xb);

  // gi = x @ wih^T + bih   (f32, non-ternary weights)
  gemm_kernel<<<dim3(3072/128, 1024/128), 256, 0, stream>>>(
      xb, wih, bih, nullptr, 0.0, 0, gi, nullptr, 1024, 3072, 1024);

  // sequential GRU -> hs (f32 residual) and xb (bf16 activations)
  gru_kernel<<<256, 512, 0, stream>>>(gi, whh, bhh, hbuf, flags, hs, xb);

  const double cnt_nd = (double)Nm * (double)Dm;
  const double cnt_vd = (double)Vm * (double)Dm;
  for (int l = 0; l < Lm; l++){
    // hidden = relu(x @ tern(syn_w)^T + syn_b)  (bf16)
    gemm_kernel<<<dim3(4096/128, 1024/128), 256, 0, stream>>>(
        xb, syn_w + (size_t)l * Nm * Dm, syn_b + (size_t)l * Nm,
        scales + 1 + l, cnt_nd, 1, nullptr, hidden, 1024, 4096, 1024);
    // out = hidden @ tern(out_w)^T + out_b  (f32)
    gemm_kernel<<<dim3(1024/128, 1024/128), 256, 0, stream>>>(
        hidden, out_w + (size_t)l * Dm * Nm, out_b + (size_t)l * Dm,
        scales + 5 + l, cnt_nd, 0, outbuf, nullptr, 1024, 1024, 4096);
    // x = LN(resid + out)  -> hs (f32) and xb (bf16)
    ln_kernel<<<1024, 256, 0, stream>>>(hs, outbuf, ln_g + (size_t)l * Dm, ln_b + (size_t)l * Dm, hs, xb);
  }
  // final LN -> xb (bf16)
  ln_kernel<<<1024, 256, 0, stream>>>(hs, nullptr, on_g, on_b, nullptr, xb);

  // logits = x @ tern(head_w)^T + head_b  (f32 -> d_out)
  gemm_kernel<<<dim3(32000/128, 1024/128), 256, 0, stream>>>(
      xb, head_w, head_b, scales + 9, cnt_vd, 0, logits, nullptr, 1024, 32000, 1024);
}

// Round 3
// 4431.189 us; speedup vs baseline: 3.1865x; 3.1865x over previous
//
#include <hip/hip_runtime.h>
#include <hip/hip_bf16.h>
#include <cstdint>
#include <cstddef>

#define Dm 1024
#define Sm 512
#define Bm 2
#define Nm 4096
#define Lm 4
#define Vm 32000

typedef __attribute__((ext_vector_type(8))) short short8;
typedef __attribute__((ext_vector_type(4))) float floatx4;

__device__ __forceinline__ unsigned short f2b(float f){
  union { float f; unsigned u; } v; v.f = f;
  unsigned r = (v.u + 0x7fffu + ((v.u >> 16) & 1u)) >> 16;
  return (unsigned short)r;
}

// Ternary decision at f64 precision: round(clip(w/s)) == sign(w) iff 2|w| > s.
__device__ __forceinline__ float tern_q(float w, double s64){
  return ((double)fabsf(w) * 2.0 > s64) ? (w < 0.f ? -1.f : 1.f) : 0.f;
}

// ---------------- abs-sum reduction (for ternary scales) ----------------
__global__ __launch_bounds__(256) void absum_part_kernel(
    const float* __restrict__ x, long n4, double* __restrict__ part)
{
  long i = (long)blockIdx.x * blockDim.x + threadIdx.x;
  long stride = (long)gridDim.x * blockDim.x;
  double s = 0.0;
  for (; i < n4; i += stride){
    float4 v = ((const float4*)x)[i];
    s += (double)fabsf(v.x) + (double)fabsf(v.y)
       + (double)fabsf(v.z) + (double)fabsf(v.w);
  }
  #pragma unroll
  for (int off = 32; off; off >>= 1) s += __shfl_down(s, off, 64);
  __shared__ double wsum[4];
  int lane = threadIdx.x & 63, wv = threadIdx.x >> 6;
  if (lane == 0) wsum[wv] = s;
  __syncthreads();
  if (threadIdx.x == 0) part[blockIdx.x] = wsum[0]+wsum[1]+wsum[2]+wsum[3];
}

__global__ __launch_bounds__(256) void absum_final_kernel(
    const double* __restrict__ part, double* __restrict__ scales)
{
  const double* p = part + (size_t)blockIdx.x * 512;
  int tid = threadIdx.x;
  double s = p[tid] + p[tid + 256];
  #pragma unroll
  for (int off = 32; off; off >>= 1) s += __shfl_down(s, off, 64);
  __shared__ double wsum[4];
  int lane = tid & 63, wv = tid >> 6;
  if (lane == 0) wsum[wv] = s;
  __syncthreads();
  if (tid == 0) scales[blockIdx.x] = wsum[0]+wsum[1]+wsum[2]+wsum[3];
}

// ---------------- ternary embedding + positional ----------------
__global__ __launch_bounds__(256) void embed_kernel(
    const int* __restrict__ ids, const float* __restrict__ emb,
    const float* __restrict__ pos, const double* __restrict__ ssum,
    unsigned short* __restrict__ xb)
{
  int row = blockIdx.x;            // b*512 + s
  int sp  = row & (Sm - 1);
  int id  = ids[row];
  double s64 = ssum[0] / ((double)Vm * (double)Dm) + 1e-8;
  float s = (float)s64;
  int d = threadIdx.x * 4;
  float4 wv = *(const float4*)(emb + (size_t)id * Dm + d);
  float4 pv = *(const float4*)(pos + (size_t)sp * Dm + d);
  float y0 = s * tern_q(wv.x, s64) + pv.x;
  float y1 = s * tern_q(wv.y, s64) + pv.y;
  float y2 = s * tern_q(wv.z, s64) + pv.z;
  float y3 = s * tern_q(wv.w, s64) + pv.w;
  ushort4 u = make_ushort4(f2b(y0), f2b(y1), f2b(y2), f2b(y3));
  *(ushort4*)(xb + (size_t)row * Dm + d) = u;
}

// ---------------- bf16 MFMA GEMM: out = act(A @ W^T * s + bias) ----------------
__global__ __launch_bounds__(256) void gemm_kernel(
    const unsigned short* __restrict__ A, const float* __restrict__ W,
    const float* __restrict__ bias, const double* __restrict__ ssum, double cnt,
    int relu, float* __restrict__ outf, unsigned short* __restrict__ outb,
    int M, int N, int K)
{
  __shared__ unsigned short As[128][40];
  __shared__ unsigned short Bs[128][40];
  int tid = threadIdx.x;
  int wave = tid >> 6, lane = tid & 63;
  int wm = wave >> 1, wn = wave & 1;
  int bm = blockIdx.y, bn = blockIdx.x;

  bool tern = (ssum != nullptr);
  double s64 = 1.0;
  float s = 1.f;
  if (tern){ s64 = ssum[0] / cnt + 1e-8; s = (float)s64; }

  int arow = tid >> 1, achunk = tid & 1;
  const unsigned short* Ag = A + (size_t)(bm * 128 + arow) * K + achunk * 16;
  const float* Wg = W + (size_t)(bn * 128 + arow) * K + achunk * 16;

  floatx4 acc[4][4];
  #pragma unroll
  for (int i = 0; i < 4; i++)
    #pragma unroll
    for (int j = 0; j < 4; j++)
      acc[i][j] = (floatx4){0.f, 0.f, 0.f, 0.f};

  for (int k0 = 0; k0 < K; k0 += 32){
    __syncthreads();
    uint4 a0 = *(const uint4*)(Ag + k0);
    uint4 a1 = *(const uint4*)(Ag + k0 + 8);
    *(uint4*)&As[arow][achunk * 16]     = a0;
    *(uint4*)&As[arow][achunk * 16 + 8] = a1;
    unsigned short tmp[16];
    #pragma unroll
    for (int q = 0; q < 4; q++){
      float4 wv = *(const float4*)(Wg + k0 + q * 4);
      float f0 = wv.x, f1 = wv.y, f2 = wv.z, f3 = wv.w;
      if (tern){
        f0 = tern_q(f0, s64);
        f1 = tern_q(f1, s64);
        f2 = tern_q(f2, s64);
        f3 = tern_q(f3, s64);
      }
      tmp[q*4+0] = f2b(f0); tmp[q*4+1] = f2b(f1);
      tmp[q*4+2] = f2b(f2); tmp[q*4+3] = f2b(f3);
    }
    *(uint4*)&Bs[arow][achunk * 16]     = *(uint4*)&tmp[0];
    *(uint4*)&Bs[arow][achunk * 16 + 8] = *(uint4*)&tmp[8];
    __syncthreads();

    int kq = lane >> 4, mr = lane & 15;
    short8 af[4], bf[4];
    #pragma unroll
    for (int i = 0; i < 4; i++) af[i] = *(const short8*)&As[wm*64 + i*16 + mr][kq*8];
    #pragma unroll
    for (int j = 0; j < 4; j++) bf[j] = *(const short8*)&Bs[wn*64 + j*16 + mr][kq*8];
    #pragma unroll
    for (int i = 0; i < 4; i++)
      #pragma unroll
      for (int j = 0; j < 4; j++)
        acc[i][j] = __builtin_amdgcn_mfma_f32_16x16x32_bf16(af[i], bf[j], acc[i][j], 0, 0, 0);
  }

  int cr = lane >> 4, cc = lane & 15;
  #pragma unroll
  for (int j = 0; j < 4; j++){
    int col = bn * 128 + wn * 64 + j * 16 + cc;
    float bv = bias ? bias[col] : 0.f;
    #pragma unroll
    for (int i = 0; i < 4; i++){
      #pragma unroll
      for (int r = 0; r < 4; r++){
        int row = bm * 128 + wm * 64 + i * 16 + cr * 4 + r;
        float v = acc[i][j][r] * s + bv;
        if (relu) v = fmaxf(v, 0.f);
        size_t idx = (size_t)row * N + col;
        if (outf) outf[idx] = v;
        if (outb) outb[idx] = f2b(v);
      }
    }
  }
}

// ---------------- persistent GRU over 512 steps ----------------
// 256 WGs x 512 threads. WG w owns h-dims [4w, 4w+4) -> 12 whh rows in registers
// (16 named float4 per thread -> guaranteed VGPRs, no scratch).
// Protocol: all cross-WG data (hbuf, flags) via RELAXED agent atomics (sc1 ->
// serviced at MALL, always coherent). Ordering: __syncthreads() drains vmcnt
// before the flag store; consumer loads issue after its spin observes the flag.
// No acquire/release fences -> no per-step L2 writeback/invalidate storms.
__global__ __launch_bounds__(512, 2) void gru_kernel(
    const float* __restrict__ gi, const float* __restrict__ whh, const float* __restrict__ bhh,
    float* __restrict__ hbuf, int* __restrict__ flags,
    float* __restrict__ hs, unsigned short* __restrict__ hsb)
{
  __shared__ __align__(16) float lds_h[2 * Dm];
  __shared__ float lds_gh[24];
  int w = blockIdx.x, tid = threadIdx.x;
  int d0 = w * 4;
  int o = tid >> 4, c = tid & 15;     // dot o (24 dots), k-chunk c
  bool active = (tid < 384);
  int b = o / 12, r = o % 12;
  int g = r >> 2, dl = r & 3;
  int wrow = g * Dm + d0 + dl;
  // thread (o,c) covers elements { j*64 + c*4 + e : j=0..15, e=0..3 } of its row
  float4 wr0 = {0,0,0,0}, wr1 = wr0, wr2 = wr0, wr3 = wr0,
         wr4 = wr0, wr5 = wr0, wr6 = wr0, wr7 = wr0,
         wr8 = wr0, wr9 = wr0, wr10 = wr0, wr11 = wr0,
         wr12 = wr0, wr13 = wr0, wr14 = wr0, wr15 = wr0;
  if (active){
    const float* wsrc = whh + (size_t)wrow * Dm + c * 4;
    wr0  = *(const float4*)(wsrc +  0*64);  wr1  = *(const float4*)(wsrc +  1*64);
    wr2  = *(const float4*)(wsrc +  2*64);  wr3  = *(const float4*)(wsrc +  3*64);
    wr4  = *(const float4*)(wsrc +  4*64);  wr5  = *(const float4*)(wsrc +  5*64);
    wr6  = *(const float4*)(wsrc +  6*64);  wr7  = *(const float4*)(wsrc +  7*64);
    wr8  = *(const float4*)(wsrc +  8*64);  wr9  = *(const float4*)(wsrc +  9*64);
    wr10 = *(const float4*)(wsrc + 10*64);  wr11 = *(const float4*)(wsrc + 11*64);
    wr12 = *(const float4*)(wsrc + 12*64);  wr13 = *(const float4*)(wsrc + 13*64);
    wr14 = *(const float4*)(wsrc + 14*64);  wr15 = *(const float4*)(wsrc + 15*64);
  }
  float bhval = (active && c == 0) ? bhh[wrow] : 0.f;

  for (int t = 0; t < Sm; t++){
    if (t > 0 && tid < 256){
      int spins = 0;
      while (__hip_atomic_load(&flags[tid], __ATOMIC_RELAXED, __HIP_MEMORY_SCOPE_AGENT) < t){
        __builtin_amdgcn_s_sleep(1);
        if (++spins > (1 << 18)) break;   // safety: degrade, don't hang
      }
    }
    __syncthreads();
    {
      const float* hsrc = hbuf + (t & 1) * 2048;
      for (int i = tid; i < 2048; i += 512)
        lds_h[i] = __hip_atomic_load(hsrc + i, __ATOMIC_RELAXED, __HIP_MEMORY_SCOPE_AGENT);
    }
    __syncthreads();
    float acc = 0.f;
    if (active){
      const float* hb = lds_h + b * Dm + c * 4;
      float4 hv;
      #define GDOT(J, W) hv = *(const float4*)(hb + (J)*64); \
          acc += W.x*hv.x + W.y*hv.y + W.z*hv.z + W.w*hv.w;
      GDOT(0,wr0)  GDOT(1,wr1)  GDOT(2,wr2)  GDOT(3,wr3)
      GDOT(4,wr4)  GDOT(5,wr5)  GDOT(6,wr6)  GDOT(7,wr7)
      GDOT(8,wr8)  GDOT(9,wr9)  GDOT(10,wr10) GDOT(11,wr11)
      GDOT(12,wr12) GDOT(13,wr13) GDOT(14,wr14) GDOT(15,wr15)
      #undef GDOT
    }
    #pragma unroll
    for (int off = 8; off; off >>= 1) acc += __shfl_xor(acc, off, 16);
    if (active && c == 0) lds_gh[o] = acc + bhval;
    __syncthreads();
    if (tid < 8){
      int bb = tid >> 2, dd = tid & 3;
      int d = d0 + dd;
      float gr = lds_gh[bb*12 + dd];
      float gz = lds_gh[bb*12 + 4 + dd];
      float gn = lds_gh[bb*12 + 8 + dd];
      const float* girow = gi + ((size_t)bb * Sm + t) * (3 * Dm);
      float ir = girow[d], iz = girow[Dm + d], inn = girow[2*Dm + d];
      float hv = lds_h[bb * Dm + d];
      float rr = 1.f / (1.f + expf(-(ir + gr)));
      float zz = 1.f / (1.f + expf(-(iz + gz)));
      float nn = tanhf(inn + rr * gn);
      float hnew = (1.f - zz) * nn + zz * hv;
      __hip_atomic_store(hbuf + ((t+1) & 1) * 2048 + bb * Dm + d, hnew,
                         __ATOMIC_RELAXED, __HIP_MEMORY_SCOPE_AGENT);
      size_t oi = ((size_t)bb * Sm + t) * Dm + d;
      hs[oi]  = hnew;
      hsb[oi] = f2b(hnew);
    }
    __syncthreads();   // drains vmcnt: hnew atomics complete at MALL before flag
    if (tid == 0)
      __hip_atomic_store(&flags[w], t + 1, __ATOMIC_RELAXED, __HIP_MEMORY_SCOPE_AGENT);
  }
}

// ---------------- layernorm (+optional residual add), writes f32 + bf16 ----------------
__global__ __launch_bounds__(256) void ln_kernel(
    float* __restrict__ resid, const float* __restrict__ addv,
    const float* __restrict__ g, const float* __restrict__ b,
    float* __restrict__ outf, unsigned short* __restrict__ outb)
{
  int row = blockIdx.x;
  int d = threadIdx.x * 4;
  size_t base = (size_t)row * Dm + d;
  float4 v = *(float4*)(resid + base);
  if (addv){
    float4 a = *(const float4*)(addv + base);
    v.x += a.x; v.y += a.y; v.z += a.z; v.w += a.w;
  }
  float sum = v.x + v.y + v.z + v.w;
  float sq  = v.x*v.x + v.y*v.y + v.z*v.z + v.w*v.w;
  #pragma unroll
  for (int off = 32; off; off >>= 1){
    sum += __shfl_down(sum, off, 64);
    sq  += __shfl_down(sq,  off, 64);
  }
  __shared__ float red[4][2];
  __shared__ float bc[2];
  int lane = threadIdx.x & 63, wv = threadIdx.x >> 6;
  if (lane == 0){ red[wv][0] = sum; red[wv][1] = sq; }
  __syncthreads();
  if (threadIdx.x == 0){
    float st = red[0][0] + red[1][0] + red[2][0] + red[3][0];
    float qt = red[0][1] + red[1][1] + red[2][1] + red[3][1];
    float mu = st * (1.f / Dm);
    float var = qt * (1.f / Dm) - mu * mu;
    bc[0] = mu; bc[1] = rsqrtf(var + 1e-5f);
  }
  __syncthreads();
  float mu = bc[0], rs = bc[1];
  float4 gv = *(const float4*)(g + d);
  float4 bv = *(const float4*)(b + d);
  float4 y;
  y.x = (v.x - mu) * rs * gv.x + bv.x;
  y.y = (v.y - mu) * rs * gv.y + bv.y;
  y.z = (v.z - mu) * rs * gv.z + bv.z;
  y.w = (v.w - mu) * rs * gv.w + bv.w;
  if (outf) *(float4*)(outf + base) = y;
  if (outb){
    ushort4 u = make_ushort4(f2b(y.x), f2b(y.y), f2b(y.z), f2b(y.w));
    *(ushort4*)(outb + base) = u;
  }
}

extern "C" void kernel_launch(void* const* d_in, const int* in_sizes, int n_in,
                              void* d_out, int out_size, void* d_ws, size_t ws_size,
                              hipStream_t stream)
{
  const int*   ids    = (const int*)  d_in[0];
  const float* emb    = (const float*)d_in[1];
  const float* pos    = (const float*)d_in[2];
  const float* wih    = (const float*)d_in[3];
  const float* whh    = (const float*)d_in[4];
  const float* bih    = (const float*)d_in[5];
  const float* bhh    = (const float*)d_in[6];
  const float* syn_w  = (const float*)d_in[7];
  const float* syn_b  = (const float*)d_in[8];
  const float* out_w  = (const float*)d_in[9];
  const float* out_b  = (const float*)d_in[10];
  const float* ln_g   = (const float*)d_in[11];
  const float* ln_b   = (const float*)d_in[12];
  const float* on_g   = (const float*)d_in[13];
  const float* on_b   = (const float*)d_in[14];
  const float* head_w = (const float*)d_in[15];
  const float* head_b = (const float*)d_in[16];
  float* logits = (float*)d_out;

  char* ws = (char*)d_ws;
  double*         scales = (double*)ws;                        // 10 doubles
  int*            flags  = (int*)  (ws + 1024);                // 256 ints
  float*          hbuf   = (float*)(ws + 8192);                // 2*2048 f32
  double*         parts  = (double*)(ws + 24576);              // 10 slots x 512 doubles (40KB)
  unsigned short* xb     = (unsigned short*)(ws + 65536);      // [1024,1024] bf16 (2MB)
  float*          hs     = (float*)(ws + ((size_t)4  << 20));  // [1024,1024] f32  (4MB)
  unsigned short* hidden = (unsigned short*)(ws + ((size_t)12 << 20)); // [1024,4096] bf16 (8MB)
  float*          outbuf = (float*)(ws + ((size_t)20 << 20));  // [1024,1024] f32  (4MB)
  float*          gi     = (float*)(ws + ((size_t)24 << 20));  // [1024,3072] f32  (12MB)

  // zero scales + flags + hbuf
  hipMemsetAsync(d_ws, 0, 24576, stream);

  // ternary scale sums — deterministic fixed-order double reduction
  {
    long n;
    n = (long)Vm * Dm;
    absum_part_kernel<<<512, 256, 0, stream>>>(emb, n / 4, parts + 0 * 512);
    for (int l = 0; l < Lm; l++){
      n = (long)Nm * Dm;
      absum_part_kernel<<<512, 256, 0, stream>>>(syn_w + (size_t)l * Nm * Dm, n / 4, parts + (size_t)(1 + l) * 512);
      absum_part_kernel<<<512, 256, 0, stream>>>(out_w + (size_t)l * Dm * Nm, n / 4, parts + (size_t)(5 + l) * 512);
    }
    n = (long)Vm * Dm;
    absum_part_kernel<<<512, 256, 0, stream>>>(head_w, n / 4, parts + 9 * 512);
    absum_final_kernel<<<10, 256, 0, stream>>>(parts, scales);
  }

  // x = tern(emb)[ids] + pos  (bf16)
  embed_kernel<<<1024, 256, 0, stream>>>(ids, emb, pos, scales, xb);

  // gi = x @ wih^T + bih   (f32, non-ternary weights)
  gemm_kernel<<<dim3(3072/128, 1024/128), 256, 0, stream>>>(
      xb, wih, bih, nullptr, 0.0, 0, gi, nullptr, 1024, 3072, 1024);

  // sequential GRU -> hs (f32 residual) and xb (bf16 activations)
  gru_kernel<<<256, 512, 0, stream>>>(gi, whh, bhh, hbuf, flags, hs, xb);

  const double cnt_nd = (double)Nm * (double)Dm;
  const double cnt_vd = (double)Vm * (double)Dm;
  for (int l = 0; l < Lm; l++){
    // hidden = relu(x @ tern(syn_w)^T + syn_b)  (bf16)
    gemm_kernel<<<dim3(4096/128, 1024/128), 256, 0, stream>>>(
        xb, syn_w + (size_t)l * Nm * Dm, syn_b + (size_t)l * Nm,
        scales + 1 + l, cnt_nd, 1, nullptr, hidden, 1024, 4096, 1024);
    // out = hidden @ tern(out_w)^T + out_b  (f32)
    gemm_kernel<<<dim3(1024/128, 1024/128), 256, 0, stream>>>(
        hidden, out_w + (size_t)l * Dm * Nm, out_b + (size_t)l * Dm,
        scales + 5 + l, cnt_nd, 0, outbuf, nullptr, 1024, 1024, 4096);
    // x = LN(resid + out)  -> hs (f32) and xb (bf16)
    ln_kernel<<<1024, 256, 0, stream>>>(hs, outbuf, ln_g + (size_t)l * Dm, ln_b + (size_t)l * Dm, hs, xb);
  }
  // final LN -> xb (bf16)
  ln_kernel<<<1024, 256, 0, stream>>>(hs, nullptr, on_g, on_b, nullptr, xb);

  // logits = x @ tern(head_w)^T + head_b  (f32 -> d_out)
  gemm_kernel<<<dim3(32000/128, 1024/128), 256, 0, stream>>>(
      xb, head_w, head_b, scales + 9, cnt_vd, 0, logits, nullptr, 1024, 32000, 1024);
}